// Round 17
// baseline (45.920 us; speedup 1.0000x reference)
//
#include <hip/hip_runtime.h>

typedef unsigned long long ull;

#define BB 16
#define NN 4096
#define NT 1024
#define EPT 4
#define MAXP 300
#define IOU_THRESH 0.7f
#define SCORE_THR 0.5f

#define FNT 512                 // K1 threads
#define FEPT (NN / FNT)         // 8 elements per thread
#define CCAP 1024               // candidate capacity
#define RTOP 512                // fast-path window
#define RW (RTOP / 64)          // 8 mask words per row
#define MBPI 16                 // K2 blocks per image (64 waves/img)
#define SNT3 512                // K3 threads (8 waves; wave 0 resolves)

__device__ __forceinline__ bool iou_ge(float ix1, float iy1, float ix2, float iy2, float ia,
                                       float x1, float y1, float x2, float y2, float aj) {
    float xx1 = fmaxf(ix1, x1);
    float yy1 = fmaxf(iy1, y1);
    float xx2 = fminf(ix2, x2);
    float yy2 = fminf(iy2, y2);
    float iw = fmaxf(__fsub_rn(xx2, xx1), 0.0f);
    float ih = fmaxf(__fsub_rn(yy2, yy1), 0.0f);
    float inter = __fmul_rn(iw, ih);
    float uni = __fsub_rn(__fadd_rn(ia, aj), inter);
    float iou = __fdiv_rn(inter, uni);
    return iou >= IOU_THRESH;
}

// ============ K1: filter + compact + bitonic (wave-local stages) + SoA emit ============
__global__ __launch_bounds__(FNT, 1) void filter_sort_kernel(const float* __restrict__ proposals,
                                                             const float* __restrict__ cls,
                                                             float* __restrict__ wx1, float* __restrict__ wy1,
                                                             float* __restrict__ wx2, float* __restrict__ wy2,
                                                             float* __restrict__ war,
                                                             unsigned* __restrict__ cidx,
                                                             unsigned* __restrict__ wnv,
                                                             unsigned* __restrict__ need0) {
    __shared__ ull ck[CCAP];                 // 8 KB
    __shared__ unsigned hist[256];
    __shared__ unsigned swsum[FNT / 64];
    __shared__ unsigned s_nv, s_t, s_abv, s_sz;

    const int b = blockIdx.x, tid = threadIdx.x;
    const unsigned lane = tid & 63, wv = tid >> 6;
    const float* Cb = cls + (size_t)b * NN * 2;
    const float4* Pb4 = (const float4*)(proposals + (size_t)b * NN * 4);

    if (tid < 256) hist[tid] = 0;
    ck[tid] = 0; ck[tid + FNT] = 0;
    if (tid == 0) s_nv = 0;
    __syncthreads();

    // ---- load scores ONCE into registers (static-indexed); count + level-1 histogram ----
    unsigned mbv[FEPT];
    unsigned lv = 0;
    #pragma unroll
    for (int c = 0; c < FEPT; ++c) {
        int i = c * FNT + tid;
        float sc = Cb[2 * i + 1];
        bool valid = sc > SCORE_THR;
        mbv[c] = valid ? (__float_as_uint(sc) | 0x80000000u) : 0u;
        if (valid) { atomicAdd(&hist[mbv[c] >> 24], 1u); ++lv; }
    }
    for (int off = 32; off > 0; off >>= 1) lv += __shfl_down(lv, off, 64);
    if (lane == 0) atomicAdd(&s_nv, lv);
    __syncthreads();

    const unsigned nv = s_nv;
    const unsigned target = nv < (unsigned)RTOP ? nv : (unsigned)RTOP;

    // ---- wave 0: suffix-scan over bins, pick t1 ----
    if (tid < 64) {
        unsigned h[4], S[4], local = 0;
        #pragma unroll
        for (int c = 0; c < 4; ++c) { h[c] = hist[tid * 4 + c]; local += h[c]; }
        unsigned inc = local;
        for (int off = 1; off < 64; off <<= 1) {
            unsigned t = __shfl_down(inc, off, 64);
            if (tid + off < 64) inc += t;
        }
        unsigned above = inc - local;
        S[3] = above + h[3];
        S[2] = S[3] + h[2];
        S[1] = S[2] + h[1];
        S[0] = S[1] + h[0];
        int bestc = -1;
        #pragma unroll
        for (int c = 3; c >= 0; --c) if (bestc < 0 && S[c] >= target) bestc = c;
        ull m = __ballot(bestc >= 0);
        int L = 63 - __builtin_clzll(m);
        if (tid == L) {
            s_t = (unsigned)(tid * 4 + bestc);
            s_abv = S[bestc] - h[bestc];
            s_sz = h[bestc];
        }
    }
    __syncthreads();
    const unsigned t1 = s_t;
    const unsigned abv1 = s_abv;
    const int lvl2 = (s_abv + s_sz > CCAP);     // uniform
    unsigned t2 = 0, Ccand;

    if (lvl2) {
        if (tid < 256) hist[tid] = 0;
        __syncthreads();
        #pragma unroll
        for (int c = 0; c < FEPT; ++c) {
            if (mbv[c] && (mbv[c] >> 24) == t1) atomicAdd(&hist[(mbv[c] >> 16) & 0xFFu], 1u);
        }
        __syncthreads();
        const unsigned target2 = target - abv1;
        if (tid < 64) {
            unsigned h[4], S[4], local = 0;
            #pragma unroll
            for (int c = 0; c < 4; ++c) { h[c] = hist[tid * 4 + c]; local += h[c]; }
            unsigned inc = local;
            for (int off = 1; off < 64; off <<= 1) {
                unsigned t = __shfl_down(inc, off, 64);
                if (tid + off < 64) inc += t;
            }
            unsigned above = inc - local;
            S[3] = above + h[3];
            S[2] = S[3] + h[2];
            S[1] = S[2] + h[1];
            S[0] = S[1] + h[0];
            int bestc = -1;
            #pragma unroll
            for (int c = 3; c >= 0; --c) if (bestc < 0 && S[c] >= target2) bestc = c;
            ull m = __ballot(bestc >= 0);
            int L = 63 - __builtin_clzll(m);
            if (tid == L) {
                s_t = (unsigned)(tid * 4 + bestc);
                s_abv = S[bestc] - h[bestc];
                s_sz = h[bestc];
            }
        }
        __syncthreads();
        t2 = s_t;
        Ccand = abv1 + s_abv + s_sz;
    } else {
        Ccand = s_abv + s_sz;
    }

    if (tid == 0) { need0[b] = (Ccand > CCAP) ? 1u : 0u; wnv[b] = nv; }

    // ---- compact candidates (superset of exact top-target) ----
    unsigned pf[FEPT];
    ull keys[FEPT];
    unsigned lc = 0;
    #pragma unroll
    for (int c = 0; c < FEPT; ++c) {
        int i = c * FNT + tid;
        unsigned p = 0; ull key = 0;
        if (mbv[c]) {
            unsigned b1 = mbv[c] >> 24;
            if (b1 > t1 || (b1 == t1 && (!lvl2 || ((mbv[c] >> 16) & 0xFFu) >= t2))) {
                p = 1;
                key = ((ull)mbv[c] << 32) | (unsigned)(~i);
            }
        }
        pf[c] = p; keys[c] = key; lc += p;
    }
    unsigned inc = lc;
    for (int off = 1; off < 64; off <<= 1) {
        unsigned o = __shfl_up(inc, off, 64);
        if (lane >= (unsigned)off) inc += o;
    }
    if (lane == 63) swsum[wv] = inc;
    __syncthreads();
    if (tid == 0) {
        unsigned run = 0;
        for (int w = 0; w < FNT / 64; ++w) { unsigned t = swsum[w]; swsum[w] = run; run += t; }
    }
    __syncthreads();
    unsigned pos = swsum[wv] + (inc - lc);
    #pragma unroll
    for (int c = 0; c < FEPT; ++c) {
        if (pf[c]) {
            if (pos < CCAP) ck[pos] = keys[c];
            ++pos;
        }
    }
    __syncthreads();

    // ---- bitonic sort (descending); only j>64 stages need block barriers ----
    // pair p=tid for j<=64 touches only elements [w*128,(w+1)*128), w=tid>>6:
    // wave-local, relies on wave64 lockstep + in-order DS pipeline.
    for (unsigned k = 2; k <= CCAP; k <<= 1) {
        for (unsigned j = k >> 1; j > 0; j >>= 1) {
            if (j > 64) __syncthreads();
            unsigned low = (unsigned)tid & (j - 1);
            unsigned i2 = (((unsigned)tid ^ low) << 1) | low;
            unsigned ixj = i2 | j;
            ull a = ck[i2], c2 = ck[ixj];
            if ((a < c2) == ((i2 & k) == 0)) { ck[i2] = c2; ck[ixj] = a; }
            if (j > 64) __syncthreads();
            else asm volatile("" ::: "memory");   // pin LDS op order within wave
        }
    }
    __syncthreads();   // emit reads cross-wave

    // ---- emit sorted top-512: SoA boxes + area + original index ----
    if (tid < RTOP) {
        const size_t base = (size_t)b * RTOP;
        ull key = ck[tid];
        unsigned oi = key ? ~(unsigned)key : 0u;
        float4 v = make_float4(0.f, 0.f, 0.f, 0.f);
        if (key) v = Pb4[oi];
        wx1[base + tid] = v.x; wy1[base + tid] = v.y;
        wx2[base + tid] = v.z; wy2[base + tid] = v.w;
        war[base + tid] = __fmul_rn(__fsub_rn(v.z, v.x), __fsub_rn(v.w, v.y));
        cidx[base + tid] = oi;
    }
}

// ============ K2: 512x512 suppression bit-matrix -> global (16 blocks/img) ============
__global__ __launch_bounds__(256) void mask512_kernel(const float* __restrict__ wx1, const float* __restrict__ wy1,
                                                      const float* __restrict__ wx2, const float* __restrict__ wy2,
                                                      const float* __restrict__ war,
                                                      const unsigned* __restrict__ wnv,
                                                      ull* __restrict__ m8) {
    __shared__ float sx1[RTOP], sy1[RTOP], sx2[RTOP], sy2[RTOP], sar[RTOP];  // 10 KB
    const int img = blockIdx.y;
    const unsigned nv = wnv[img];
    const unsigned R2 = nv < (unsigned)RTOP ? nv : (unsigned)RTOP;
    if (R2 == 0) return;
    const int tid = threadIdx.x;
    const size_t base = (size_t)img * RTOP;

    for (int idx = tid; idx < RTOP; idx += 256) {
        sx1[idx] = wx1[base + idx];
        sy1[idx] = wy1[base + idx];
        sx2[idx] = wx2[base + idx];
        sy2[idx] = wy2[base + idx];
        sar[idx] = war[base + idx];
    }
    __syncthreads();

    const unsigned lane = tid & 63;
    const unsigned wvimg = blockIdx.x * 4 + (tid >> 6);   // 0..MBPI*4-1 per image
    const unsigned wlastR = (R2 - 1) >> 6;
    ull* mimg = m8 + base * RW;

    for (unsigned i = wvimg; i < R2; i += MBPI * 4) {     // interleaved: balances triangle
        float ix1 = sx1[i], iy1 = sy1[i], ix2 = sx2[i], iy2 = sy2[i], ia = sar[i];
        const unsigned w0 = i >> 6;
        ull my = 0;
        for (unsigned w = w0; w <= wlastR; ++w) {
            unsigned jj = (w << 6) | lane;
            bool pred = (jj > i) && iou_ge(ix1, iy1, ix2, iy2, ia,
                                           sx1[jj], sy1[jj], sx2[jj], sy2[jj], sar[jj]);
            ull bal = __ballot(pred);
            if (lane == w) my = bal;
        }
        if (lane < RW) {
            ull val = (lane >= w0 && lane <= wlastR) ? my : 0ULL;
            mimg[(size_t)i * RW + lane] = val;            // all 8 words defined (zeros below diag)
        }
    }
}

// ============ K3: bit-serial resolve, batched named-var dbuf chain + rank-select ============
#define RLD8(P, BASE)                                                         \
    P##0 = rowp[(BASE + 0) * RW + w]; P##1 = rowp[(BASE + 1) * RW + w];       \
    P##2 = rowp[(BASE + 2) * RW + w]; P##3 = rowp[(BASE + 3) * RW + w];       \
    P##4 = rowp[(BASE + 4) * RW + w]; P##5 = rowp[(BASE + 5) * RW + w];       \
    P##6 = rowp[(BASE + 6) * RW + w]; P##7 = rowp[(BASE + 7) * RW + w];

#define RCH1(V, I)                                                            \
    { ull tk_ = ((S >> (I)) & 1ULL) ^ 1ULL; S |= (V) & (0ULL - tk_); }

#define RCH8(P, BASE)                                                         \
    RCH1(P##0, BASE + 0) RCH1(P##1, BASE + 1) RCH1(P##2, BASE + 2)            \
    RCH1(P##3, BASE + 3) RCH1(P##4, BASE + 4) RCH1(P##5, BASE + 5)            \
    RCH1(P##6, BASE + 6) RCH1(P##7, BASE + 7)

__global__ __launch_bounds__(SNT3, 1) void scan_out_kernel(const float* __restrict__ proposals,
                                                           const float* __restrict__ cls,
                                                           const float* __restrict__ wx1, const float* __restrict__ wy1,
                                                           const float* __restrict__ wx2, const float* __restrict__ wy2,
                                                           const unsigned* __restrict__ cidx,
                                                           const unsigned* __restrict__ wnv,
                                                           const unsigned* __restrict__ need0,
                                                           unsigned* __restrict__ need1,
                                                           const ull* __restrict__ m8,
                                                           float* __restrict__ out) {
    __shared__ ull smask[RTOP][RW];                       // 32 KB
    __shared__ ull kmask[RW];
    __shared__ unsigned s_nk;
    const int b = blockIdx.x, tid = threadIdx.x;
    const unsigned lane = tid & 63;
    const unsigned nv = wnv[b];
    const unsigned R2 = nv < (unsigned)RTOP ? nv : (unsigned)RTOP;
    const size_t base = (size_t)b * RTOP;
    const float* Cb = cls + (size_t)b * NN * 2;
    const float4* Pb4 = (const float4*)(proposals + (size_t)b * NN * 4);

    // ---- stage mask into LDS (8 waves, coalesced) + zero kmask ----
    {
        const ull* mimg = m8 + base * RW;
        ull* smflat = &smask[0][0];
        #pragma unroll
        for (int k = 0; k < (RTOP * RW) / SNT3; ++k)
            smflat[k * SNT3 + tid] = mimg[k * SNT3 + tid];
    }
    if (tid < RW) kmask[tid] = 0ULL;
    __syncthreads();

    // ---- wave 0: greedy resolve, word-at-a-time (loads batched ahead of chain) ----
    if (tid < 64) {
        const unsigned myw = lane & (RW - 1);
        ull sup;
        {
            unsigned lb = myw << 6;
            if (lb >= nv) sup = ~0ULL;
            else if (lb + 64 <= nv) sup = 0ULL;
            else sup = (~0ULL) << (nv - lb);
        }

        unsigned cnt = 0;
        const unsigned nw = (R2 + 63) >> 6;
        for (unsigned w = 0; w < nw; ++w) {
            ull S = __shfl(sup, (int)w, 64);
            const ull* rowp = &smask[w << 6][0];
            {
                ull a0, a1, a2, a3, a4, a5, a6, a7;
                ull b0, b1, b2, b3, b4, b5, b6, b7;
                RLD8(a, 0)
                RLD8(b, 8)
                RCH8(a, 0)
                RLD8(a, 16)
                RCH8(b, 8)
                RLD8(b, 24)
                RCH8(a, 16)
                RLD8(a, 32)
                RCH8(b, 24)
                RLD8(b, 40)
                RCH8(a, 32)
                RLD8(a, 48)
                RCH8(b, 40)
                RLD8(b, 56)
                RCH8(a, 48)
                RCH8(b, 56)
            }
            ull K = ~S;
            if (lane == 0) kmask[w] = K;
            cnt += (unsigned)__popcll(K);
            if (cnt >= MAXP) break;
            // cross-apply kept rows to this lane's word (independent loads, pipelined)
            ull acc = 0;
            #pragma unroll
            for (int i = 0; i < 64; ++i) {
                ull t = (K >> i) & 1ULL;
                acc |= rowp[i * RW + myw] & (0ULL - t);
            }
            sup |= acc;
        }
        if (lane == 0) {
            s_nk = cnt;
            need1[b] = need0[b] | ((cnt < MAXP && nv > (unsigned)RTOP) ? 1u : 0u);
        }
    }
    __syncthreads();

    // ---- output via rank-select over kmask (all 8 waves) ----
    const unsigned nk = s_nk;
    for (unsigned t = tid; t < MAXP; t += SNT3) {
        float x1, y1, x2, y2; unsigned oi;
        if (nk == 0) {
            oi = NN - 1;                                      // nv==0 path (validated semantics)
            float4 v = Pb4[oi];
            x1 = v.x; y1 = v.y; x2 = v.z; y2 = v.w;
        } else {
            unsigned r = (t < nk) ? t : nk - 1;
            unsigned w = 0;
            while (true) {                                    // r < cnt guarantees exit
                unsigned pc = (unsigned)__popcll(kmask[w]);
                if (r < pc) break;
                r -= pc; ++w;
            }
            ull K = kmask[w];
            unsigned p2 = 0, c;
            c = (unsigned)__popcll(K & 0xFFFFFFFFULL); if (r >= c) { r -= c; p2 += 32; K >>= 32; }
            c = (unsigned)__popcll(K & 0xFFFFULL);     if (r >= c) { r -= c; p2 += 16; K >>= 16; }
            c = (unsigned)__popcll(K & 0xFFULL);       if (r >= c) { r -= c; p2 += 8;  K >>= 8; }
            c = (unsigned)__popcll(K & 0xFULL);        if (r >= c) { r -= c; p2 += 4;  K >>= 4; }
            c = (unsigned)__popcll(K & 0x3ULL);        if (r >= c) { r -= c; p2 += 2;  K >>= 2; }
            c = (unsigned)__popcll(K & 0x1ULL);        if (r >= c) { r -= c; p2 += 1; }
            unsigned p = (w << 6) | p2;
            oi = cidx[base + p];
            x1 = wx1[base + p]; y1 = wy1[base + p];
            x2 = wx2[base + p]; y2 = wy2[base + p];
        }
        float sc = Cb[2 * oi + 1];
        float* ob = out + ((size_t)b * MAXP + t) * 4;
        ob[0] = x1; ob[1] = y1; ob[2] = x2; ob[3] = y2;
        out[(size_t)BB * MAXP * 4 + (size_t)b * MAXP + t] = sc;
    }
}

// ============ Guarded full fallback (round-2 monolithic, validated) ============
#define CH 64
#define TPC (CH / EPT)
__global__ __launch_bounds__(NT) void nms_fallback(const float* __restrict__ proposals,
                                                   const float* __restrict__ cls,
                                                   const unsigned* __restrict__ need1,
                                                   float* __restrict__ out) {
    __shared__ unsigned long long skeys[NN];
    __shared__ unsigned char ssup[NN];
    __shared__ float cbx1[2][CH], cby1[2][CH], cbx2[2][CH], cby2[2][CH], cbar[2][CH];
    __shared__ unsigned long long skept[2];
    __shared__ unsigned int ssel[MAXP];
    __shared__ unsigned int swsum[NT / 64];
    __shared__ unsigned int s_nvalid;
    __shared__ unsigned int s_nk;

    const int b = blockIdx.x;
    if (need1 && !need1[b]) return;
    const int tid = threadIdx.x;
    const float* Pb = proposals + (size_t)b * NN * 4;
    const float* Cb = cls + (size_t)b * NN * 2;

    if (tid == 0) s_nvalid = 0;
    __syncthreads();

    unsigned lv = 0;
    for (int i = tid; i < NN; i += NT) {
        float sc = Cb[i * 2 + 1];
        bool valid = sc > SCORE_THR;
        unsigned mb = valid ? (__float_as_uint(sc) | 0x80000000u) : 0u;
        skeys[i] = ((unsigned long long)mb << 32) | (unsigned)(~i);
        lv += valid ? 1u : 0u;
    }
    for (int off = 32; off > 0; off >>= 1) lv += __shfl_down(lv, off, 64);
    if ((tid & 63) == 0) atomicAdd(&s_nvalid, lv);

    for (unsigned k = 2; k <= NN; k <<= 1) {
        for (unsigned j = k >> 1; j > 0; j >>= 1) {
            __syncthreads();
            for (unsigned p = tid; p < NN / 2; p += NT) {
                unsigned low = p & (j - 1);
                unsigned i = ((p ^ low) << 1) | low;
                unsigned ixj = i | j;
                unsigned long long a = skeys[i], c = skeys[ixj];
                if ((a < c) == ((i & k) == 0)) { skeys[i] = c; skeys[ixj] = a; }
            }
        }
    }
    __syncthreads();

    const unsigned n_valid = s_nvalid;

    unsigned ordj[EPT];
    float bx1[EPT], by1[EPT], bx2[EPT], by2[EPT], bar[EPT];
    int rflag[EPT];
    for (int c2 = 0; c2 < EPT; ++c2) {
        int j = tid * EPT + c2;
        unsigned oi = ~(unsigned)skeys[j];
        ordj[c2] = oi;
        const float* P = Pb + (size_t)oi * 4;
        float x1 = P[0], y1 = P[1], x2 = P[2], y2 = P[3];
        bx1[c2] = x1; by1[c2] = y1; bx2[c2] = x2; by2[c2] = y2;
        bar[c2] = __fmul_rn(__fsub_rn(x2, x1), __fsub_rn(y2, y1));
        int sup = (j < (int)n_valid) ? 0 : 1;
        rflag[c2] = sup;
        ssup[j] = (unsigned char)sup;
    }

    const unsigned nch = (n_valid + CH - 1) / CH;
    for (unsigned c = 0; c < nch; ++c) {
        const int p = (int)(c & 1);
        if (tid >= (int)(TPC * c) && tid < (int)(TPC * (c + 1))) {
            int bse = (tid - TPC * c) * EPT;
            #pragma unroll
            for (int c2 = 0; c2 < EPT; ++c2) {
                int l = bse + c2;
                cbx1[p][l] = bx1[c2]; cby1[p][l] = by1[c2];
                cbx2[p][l] = bx2[c2]; cby2[p][l] = by2[c2];
                cbar[p][l] = bar[c2];
            }
        }
        __syncthreads();

        if (tid < CH) {
            const int l = tid;
            const int j = (int)(c * CH) + l;
            float x1 = cbx1[p][l], y1 = cby1[p][l], x2 = cbx2[p][l], y2 = cby2[p][l];
            float ar = cbar[p][l];
            int supl = ssup[j];
            unsigned long long row = 0ULL;
            for (int m = l + 1; m < CH; ++m) {
                bool s = iou_ge(x1, y1, x2, y2, ar,
                                cbx1[p][m], cby1[p][m], cbx2[p][m], cby2[p][m], cbar[p][m]);
                if (s) row |= (1ULL << m);
            }
            unsigned long long S = __ballot(supl != 0);
            for (int i = 0; i < CH; ++i) {
                unsigned long long ri = __shfl(row, i, 64);
                if (!((S >> i) & 1ULL)) S |= ri;
            }
            ssup[j] = (unsigned char)((S >> l) & 1ULL);
            if (l == 0) skept[p] = ~S;
        }
        __syncthreads();

        const int myFirst = tid * EPT;
        if (myFirst >= (int)(CH * (c + 1)) &&
            !(rflag[0] & rflag[1] & rflag[2] & rflag[3])) {
            unsigned long long K = skept[p];
            while (K) {
                int m = __builtin_ctzll(K);
                K &= K - 1;
                float mx1 = cbx1[p][m], my1 = cby1[p][m];
                float mx2 = cbx2[p][m], my2 = cby2[p][m];
                float ma = cbar[p][m];
                #pragma unroll
                for (int c2 = 0; c2 < EPT; ++c2) {
                    if (!rflag[c2]) {
                        bool s = iou_ge(mx1, my1, mx2, my2, ma,
                                        bx1[c2], by1[c2], bx2[c2], by2[c2], bar[c2]);
                        if (s) { rflag[c2] = 1; ssup[myFirst + c2] = 1; }
                    }
                }
            }
        }
    }
    __syncthreads();

    unsigned kflag[EPT];
    unsigned lc = 0;
    for (int c2 = 0; c2 < EPT; ++c2) {
        int j = tid * EPT + c2;
        kflag[c2] = ssup[j] ? 0u : 1u;
        lc += kflag[c2];
    }
    unsigned lane = tid & 63, wid = tid >> 6;
    unsigned inc = lc;
    for (int off = 1; off < 64; off <<= 1) {
        unsigned o = __shfl_up(inc, off, 64);
        if (lane >= (unsigned)off) inc += o;
    }
    if (lane == 63) swsum[wid] = inc;
    __syncthreads();
    if (tid == 0) {
        unsigned run = 0;
        for (int w = 0; w < NT / 64; ++w) { unsigned t = swsum[w]; swsum[w] = run; run += t; }
        s_nk = run;
    }
    __syncthreads();
    unsigned bse = swsum[wid] + (inc - lc);
    for (int c2 = 0; c2 < EPT; ++c2) {
        if (kflag[c2]) {
            if (bse < MAXP) ssel[bse] = ordj[c2];
            ++bse;
        }
    }
    const unsigned nk_pre = s_nk;
    __syncthreads();

    if (tid < MAXP) {
        if (nk_pre == 0) {
            ssel[tid] = ~(unsigned)skeys[NN - 1];
        } else if (tid >= nk_pre) {
            ssel[tid] = ssel[nk_pre - 1];
        }
    }
    __syncthreads();

    if (tid < MAXP) {
        unsigned si = ssel[tid];
        const float* P = Pb + (size_t)si * 4;
        float* ob = out + ((size_t)b * MAXP + tid) * 4;
        ob[0] = P[0]; ob[1] = P[1]; ob[2] = P[2]; ob[3] = P[3];
        out[(size_t)BB * MAXP * 4 + (size_t)b * MAXP + tid] = Cb[si * 2 + 1];
    }
}

extern "C" void kernel_launch(void* const* d_in, const int* in_sizes, int n_in,
                              void* d_out, int out_size, void* d_ws, size_t ws_size,
                              hipStream_t stream) {
    const float* proposals = (const float*)d_in[0];
    const float* cls = (const float*)d_in[1];
    float* out = (float*)d_out;

    const size_t S = (size_t)BB * RTOP;
    const size_t need_sz = S * RW * sizeof(ull)       // m8
                         + S * 5 * sizeof(float)      // SoA
                         + S * sizeof(unsigned)       // cidx
                         + 3 * BB * sizeof(unsigned) + 256;
    if (ws_size < need_sz) {
        nms_fallback<<<BB, NT, 0, stream>>>(proposals, cls, (const unsigned*)nullptr, out);
        return;
    }

    ull* m8 = (ull*)d_ws;                             // 512 KB
    float* wx1 = (float*)(m8 + S * RW);
    float* wy1 = wx1 + S;
    float* wx2 = wy1 + S;
    float* wy2 = wx2 + S;
    float* war = wy2 + S;
    unsigned* cidx = (unsigned*)(war + S);
    unsigned* wnv = cidx + S;
    unsigned* need0 = wnv + BB;
    unsigned* need1 = need0 + BB;

    filter_sort_kernel<<<BB, FNT, 0, stream>>>(proposals, cls, wx1, wy1, wx2, wy2, war,
                                               cidx, wnv, need0);
    mask512_kernel<<<dim3(MBPI, BB), 256, 0, stream>>>(wx1, wy1, wx2, wy2, war, wnv, m8);
    scan_out_kernel<<<BB, SNT3, 0, stream>>>(proposals, cls, wx1, wy1, wx2, wy2,
                                             cidx, wnv, need0, need1, m8, out);
    nms_fallback<<<BB, NT, 0, stream>>>(proposals, cls, need1, out);   // no-op unless flagged
}

// Round 18
// 43.804 us; speedup vs baseline: 1.0483x; 1.0483x over previous
//
#include <hip/hip_runtime.h>

typedef unsigned long long ull;

#define BB 16
#define NN 4096
#define NT 1024
#define EPT 4
#define MAXP 300
#define IOU_THRESH 0.7f
#define SCORE_THR 0.5f

#define FNT 512                 // K1 threads
#define FEPT (NN / FNT)         // 8 elements per thread
#define CCAP 1024               // candidate capacity
#define RTOP 512                // fast-path window
#define RW (RTOP / 64)          // 8 mask words per row
#define MBPI 16                 // K2 blocks per image (64 waves/img)
#define SNT3 512                // K3 threads (8 waves; wave 0 resolves)

__device__ __forceinline__ bool iou_ge(float ix1, float iy1, float ix2, float iy2, float ia,
                                       float x1, float y1, float x2, float y2, float aj) {
    float xx1 = fmaxf(ix1, x1);
    float yy1 = fmaxf(iy1, y1);
    float xx2 = fminf(ix2, x2);
    float yy2 = fminf(iy2, y2);
    float iw = fmaxf(__fsub_rn(xx2, xx1), 0.0f);
    float ih = fmaxf(__fsub_rn(yy2, yy1), 0.0f);
    float inter = __fmul_rn(iw, ih);
    float uni = __fsub_rn(__fadd_rn(ia, aj), inter);
    float iou = __fdiv_rn(inter, uni);
    return iou >= IOU_THRESH;
}

// ============ K1: threshold-filter + compact + sort + SoA emit (round-11 verbatim) ============
__global__ __launch_bounds__(FNT, 1) void filter_sort_kernel(const float* __restrict__ proposals,
                                                             const float* __restrict__ cls,
                                                             float* __restrict__ wx1, float* __restrict__ wy1,
                                                             float* __restrict__ wx2, float* __restrict__ wy2,
                                                             float* __restrict__ war,
                                                             unsigned* __restrict__ cidx,
                                                             unsigned* __restrict__ wnv,
                                                             unsigned* __restrict__ need0) {
    __shared__ ull ck[CCAP];                 // 8 KB
    __shared__ unsigned hist[256];
    __shared__ unsigned swsum[FNT / 64];
    __shared__ unsigned s_nv, s_t, s_abv, s_sz;

    const int b = blockIdx.x, tid = threadIdx.x;
    const unsigned lane = tid & 63, wv = tid >> 6;
    const float* Cb = cls + (size_t)b * NN * 2;
    const float4* Pb4 = (const float4*)(proposals + (size_t)b * NN * 4);

    if (tid < 256) hist[tid] = 0;
    ck[tid] = 0; ck[tid + FNT] = 0;
    if (tid == 0) s_nv = 0;
    __syncthreads();

    // ---- pass 1: valid count + level-1 histogram (bin1 = mb>>24, monotone) ----
    unsigned lv = 0;
    #pragma unroll
    for (int c = 0; c < FEPT; ++c) {
        int i = c * FNT + tid;
        float sc = Cb[2 * i + 1];
        if (sc > SCORE_THR) {
            unsigned mb = __float_as_uint(sc) | 0x80000000u;
            atomicAdd(&hist[mb >> 24], 1u);
            ++lv;
        }
    }
    for (int off = 32; off > 0; off >>= 1) lv += __shfl_down(lv, off, 64);
    if (lane == 0) atomicAdd(&s_nv, lv);
    __syncthreads();

    const unsigned nv = s_nv;
    const unsigned target = nv < (unsigned)RTOP ? nv : (unsigned)RTOP;

    // ---- wave 0: suffix-scan over bins, pick t1 ----
    if (tid < 64) {
        unsigned h[4], S[4], local = 0;
        #pragma unroll
        for (int c = 0; c < 4; ++c) { h[c] = hist[tid * 4 + c]; local += h[c]; }
        unsigned inc = local;
        for (int off = 1; off < 64; off <<= 1) {
            unsigned t = __shfl_down(inc, off, 64);
            if (tid + off < 64) inc += t;
        }
        unsigned above = inc - local;
        S[3] = above + h[3];
        S[2] = S[3] + h[2];
        S[1] = S[2] + h[1];
        S[0] = S[1] + h[0];
        int bestc = -1;
        #pragma unroll
        for (int c = 3; c >= 0; --c) if (bestc < 0 && S[c] >= target) bestc = c;
        ull m = __ballot(bestc >= 0);
        int L = 63 - __builtin_clzll(m);
        if (tid == L) {
            s_t = (unsigned)(tid * 4 + bestc);
            s_abv = S[bestc] - h[bestc];
            s_sz = h[bestc];
        }
    }
    __syncthreads();
    const unsigned t1 = s_t;
    const unsigned abv1 = s_abv;
    const int lvl2 = (s_abv + s_sz > CCAP);     // uniform
    unsigned t2 = 0, Ccand;

    if (lvl2) {
        if (tid < 256) hist[tid] = 0;
        __syncthreads();
        #pragma unroll
        for (int c = 0; c < FEPT; ++c) {
            int i = c * FNT + tid;
            float sc = Cb[2 * i + 1];
            if (sc > SCORE_THR) {
                unsigned mb = __float_as_uint(sc) | 0x80000000u;
                if ((mb >> 24) == t1) atomicAdd(&hist[(mb >> 16) & 0xFFu], 1u);
            }
        }
        __syncthreads();
        const unsigned target2 = target - abv1;
        if (tid < 64) {
            unsigned h[4], S[4], local = 0;
            #pragma unroll
            for (int c = 0; c < 4; ++c) { h[c] = hist[tid * 4 + c]; local += h[c]; }
            unsigned inc = local;
            for (int off = 1; off < 64; off <<= 1) {
                unsigned t = __shfl_down(inc, off, 64);
                if (tid + off < 64) inc += t;
            }
            unsigned above = inc - local;
            S[3] = above + h[3];
            S[2] = S[3] + h[2];
            S[1] = S[2] + h[1];
            S[0] = S[1] + h[0];
            int bestc = -1;
            #pragma unroll
            for (int c = 3; c >= 0; --c) if (bestc < 0 && S[c] >= target2) bestc = c;
            ull m = __ballot(bestc >= 0);
            int L = 63 - __builtin_clzll(m);
            if (tid == L) {
                s_t = (unsigned)(tid * 4 + bestc);
                s_abv = S[bestc] - h[bestc];
                s_sz = h[bestc];
            }
        }
        __syncthreads();
        t2 = s_t;
        Ccand = abv1 + s_abv + s_sz;
    } else {
        Ccand = s_abv + s_sz;
    }

    if (tid == 0) { need0[b] = (Ccand > CCAP) ? 1u : 0u; wnv[b] = nv; }

    // ---- compact candidates (superset of exact top-target) ----
    unsigned pf[FEPT];
    ull keys[FEPT];
    unsigned lc = 0;
    #pragma unroll
    for (int c = 0; c < FEPT; ++c) {
        int i = c * FNT + tid;
        float sc = Cb[2 * i + 1];
        unsigned p = 0; ull key = 0;
        if (sc > SCORE_THR) {
            unsigned mb = __float_as_uint(sc) | 0x80000000u;
            unsigned b1 = mb >> 24;
            if (b1 > t1 || (b1 == t1 && (!lvl2 || ((mb >> 16) & 0xFFu) >= t2))) {
                p = 1;
                key = ((ull)mb << 32) | (unsigned)(~i);
            }
        }
        pf[c] = p; keys[c] = key; lc += p;
    }
    unsigned inc = lc;
    for (int off = 1; off < 64; off <<= 1) {
        unsigned o = __shfl_up(inc, off, 64);
        if (lane >= (unsigned)off) inc += o;
    }
    if (lane == 63) swsum[wv] = inc;
    __syncthreads();
    if (tid == 0) {
        unsigned run = 0;
        for (int w = 0; w < FNT / 64; ++w) { unsigned t = swsum[w]; swsum[w] = run; run += t; }
    }
    __syncthreads();
    unsigned pos = swsum[wv] + (inc - lc);
    #pragma unroll
    for (int c = 0; c < FEPT; ++c) {
        if (pf[c]) {
            if (pos < CCAP) ck[pos] = keys[c];
            ++pos;
        }
    }
    __syncthreads();

    // ---- bitonic sort of CCAP keys (descending), pair-enumerated ----
    for (unsigned k = 2; k <= CCAP; k <<= 1) {
        for (unsigned j = k >> 1; j > 0; j >>= 1) {
            unsigned p = tid;                     // exactly CCAP/2 pairs = FNT threads
            unsigned low = p & (j - 1);
            unsigned i2 = ((p ^ low) << 1) | low;
            unsigned ixj = i2 | j;
            ull a = ck[i2], c2 = ck[ixj];
            if ((a < c2) == ((i2 & k) == 0)) { ck[i2] = c2; ck[ixj] = a; }
            __syncthreads();
        }
    }

    // ---- emit sorted top-512: SoA boxes + area + original index ----
    if (tid < RTOP) {
        const size_t base = (size_t)b * RTOP;
        ull key = ck[tid];
        unsigned oi = key ? ~(unsigned)key : 0u;
        float4 v = make_float4(0.f, 0.f, 0.f, 0.f);
        if (key) v = Pb4[oi];
        wx1[base + tid] = v.x; wy1[base + tid] = v.y;
        wx2[base + tid] = v.z; wy2[base + tid] = v.w;
        war[base + tid] = __fmul_rn(__fsub_rn(v.z, v.x), __fsub_rn(v.w, v.y));
        cidx[base + tid] = oi;
    }
}

// ============ K2: 512x512 suppression bit-matrix -> global (16 blocks/img) ============
__global__ __launch_bounds__(256) void mask512_kernel(const float* __restrict__ wx1, const float* __restrict__ wy1,
                                                      const float* __restrict__ wx2, const float* __restrict__ wy2,
                                                      const float* __restrict__ war,
                                                      const unsigned* __restrict__ wnv,
                                                      ull* __restrict__ m8) {
    __shared__ float sx1[RTOP], sy1[RTOP], sx2[RTOP], sy2[RTOP], sar[RTOP];  // 10 KB
    const int img = blockIdx.y;
    const unsigned nv = wnv[img];
    const unsigned R2 = nv < (unsigned)RTOP ? nv : (unsigned)RTOP;
    if (R2 == 0) return;
    const int tid = threadIdx.x;
    const size_t base = (size_t)img * RTOP;

    for (int idx = tid; idx < RTOP; idx += 256) {
        sx1[idx] = wx1[base + idx];
        sy1[idx] = wy1[base + idx];
        sx2[idx] = wx2[base + idx];
        sy2[idx] = wy2[base + idx];
        sar[idx] = war[base + idx];
    }
    __syncthreads();

    const unsigned lane = tid & 63;
    const unsigned wvimg = blockIdx.x * 4 + (tid >> 6);   // 0..MBPI*4-1 per image
    const unsigned wlastR = (R2 - 1) >> 6;
    ull* mimg = m8 + base * RW;

    for (unsigned i = wvimg; i < R2; i += MBPI * 4) {     // interleaved: balances triangle
        float ix1 = sx1[i], iy1 = sy1[i], ix2 = sx2[i], iy2 = sy2[i], ia = sar[i];
        const unsigned w0 = i >> 6;
        ull my = 0;
        for (unsigned w = w0; w <= wlastR; ++w) {
            unsigned jj = (w << 6) | lane;
            bool pred = (jj > i) && iou_ge(ix1, iy1, ix2, iy2, ia,
                                           sx1[jj], sy1[jj], sx2[jj], sy2[jj], sar[jj]);
            ull bal = __ballot(pred);
            if (lane == w) my = bal;
        }
        if (lane < RW) {
            ull val = (lane >= w0 && lane <= wlastR) ? my : 0ULL;
            mimg[(size_t)i * RW + lane] = val;            // all 8 words defined (zeros below diag)
        }
    }
}

// ============ K3: bit-serial resolve, batched named-var dbuf chain + rank-select ============
#define RLD8(P, BASE)                                                         \
    P##0 = rowp[(BASE + 0) * RW + w]; P##1 = rowp[(BASE + 1) * RW + w];       \
    P##2 = rowp[(BASE + 2) * RW + w]; P##3 = rowp[(BASE + 3) * RW + w];       \
    P##4 = rowp[(BASE + 4) * RW + w]; P##5 = rowp[(BASE + 5) * RW + w];       \
    P##6 = rowp[(BASE + 6) * RW + w]; P##7 = rowp[(BASE + 7) * RW + w];

#define RCH1(V, I)                                                            \
    { ull tk_ = ((S >> (I)) & 1ULL) ^ 1ULL; S |= (V) & (0ULL - tk_); }

#define RCH8(P, BASE)                                                         \
    RCH1(P##0, BASE + 0) RCH1(P##1, BASE + 1) RCH1(P##2, BASE + 2)            \
    RCH1(P##3, BASE + 3) RCH1(P##4, BASE + 4) RCH1(P##5, BASE + 5)            \
    RCH1(P##6, BASE + 6) RCH1(P##7, BASE + 7)

__global__ __launch_bounds__(SNT3, 1) void scan_out_kernel(const float* __restrict__ proposals,
                                                           const float* __restrict__ cls,
                                                           const float* __restrict__ wx1, const float* __restrict__ wy1,
                                                           const float* __restrict__ wx2, const float* __restrict__ wy2,
                                                           const unsigned* __restrict__ cidx,
                                                           const unsigned* __restrict__ wnv,
                                                           const unsigned* __restrict__ need0,
                                                           unsigned* __restrict__ need1,
                                                           const ull* __restrict__ m8,
                                                           float* __restrict__ out) {
    __shared__ ull smask[RTOP][RW];                       // 32 KB
    __shared__ ull kmask[RW];
    __shared__ unsigned s_nk;
    const int b = blockIdx.x, tid = threadIdx.x;
    const unsigned lane = tid & 63;
    const unsigned nv = wnv[b];
    const unsigned R2 = nv < (unsigned)RTOP ? nv : (unsigned)RTOP;
    const size_t base = (size_t)b * RTOP;
    const float* Cb = cls + (size_t)b * NN * 2;
    const float4* Pb4 = (const float4*)(proposals + (size_t)b * NN * 4);

    // ---- stage mask into LDS (8 waves, coalesced) + zero kmask ----
    {
        const ull* mimg = m8 + base * RW;
        ull* smflat = &smask[0][0];
        #pragma unroll
        for (int k = 0; k < (RTOP * RW) / SNT3; ++k)
            smflat[k * SNT3 + tid] = mimg[k * SNT3 + tid];
    }
    if (tid < RW) kmask[tid] = 0ULL;
    __syncthreads();

    // ---- wave 0: greedy resolve, word-at-a-time (loads batched ahead of chain) ----
    if (tid < 64) {
        const unsigned myw = lane & (RW - 1);
        ull sup;
        {
            unsigned lb = myw << 6;
            if (lb >= nv) sup = ~0ULL;
            else if (lb + 64 <= nv) sup = 0ULL;
            else sup = (~0ULL) << (nv - lb);
        }

        unsigned cnt = 0;
        const unsigned nw = (R2 + 63) >> 6;
        for (unsigned w = 0; w < nw; ++w) {
            ull S = __shfl(sup, (int)w, 64);
            const ull* rowp = &smask[w << 6][0];
            {
                ull a0, a1, a2, a3, a4, a5, a6, a7;
                ull b0, b1, b2, b3, b4, b5, b6, b7;
                RLD8(a, 0)
                RLD8(b, 8)
                RCH8(a, 0)
                RLD8(a, 16)
                RCH8(b, 8)
                RLD8(b, 24)
                RCH8(a, 16)
                RLD8(a, 32)
                RCH8(b, 24)
                RLD8(b, 40)
                RCH8(a, 32)
                RLD8(a, 48)
                RCH8(b, 40)
                RLD8(b, 56)
                RCH8(a, 48)
                RCH8(b, 56)
            }
            ull K = ~S;
            if (lane == 0) kmask[w] = K;
            cnt += (unsigned)__popcll(K);
            if (cnt >= MAXP) break;
            // cross-apply kept rows to this lane's word (independent loads, pipelined)
            ull acc = 0;
            #pragma unroll
            for (int i = 0; i < 64; ++i) {
                ull t = (K >> i) & 1ULL;
                acc |= rowp[i * RW + myw] & (0ULL - t);
            }
            sup |= acc;
        }
        if (lane == 0) {
            s_nk = cnt;
            need1[b] = need0[b] | ((cnt < MAXP && nv > (unsigned)RTOP) ? 1u : 0u);
        }
    }
    __syncthreads();

    // ---- output via rank-select over kmask (all 8 waves) ----
    const unsigned nk = s_nk;
    for (unsigned t = tid; t < MAXP; t += SNT3) {
        float x1, y1, x2, y2; unsigned oi;
        if (nk == 0) {
            oi = NN - 1;                                      // nv==0 path (validated semantics)
            float4 v = Pb4[oi];
            x1 = v.x; y1 = v.y; x2 = v.z; y2 = v.w;
        } else {
            unsigned r = (t < nk) ? t : nk - 1;
            unsigned w = 0;
            while (true) {                                    // r < cnt guarantees exit
                unsigned pc = (unsigned)__popcll(kmask[w]);
                if (r < pc) break;
                r -= pc; ++w;
            }
            ull K = kmask[w];
            unsigned p2 = 0, c;
            c = (unsigned)__popcll(K & 0xFFFFFFFFULL); if (r >= c) { r -= c; p2 += 32; K >>= 32; }
            c = (unsigned)__popcll(K & 0xFFFFULL);     if (r >= c) { r -= c; p2 += 16; K >>= 16; }
            c = (unsigned)__popcll(K & 0xFFULL);       if (r >= c) { r -= c; p2 += 8;  K >>= 8; }
            c = (unsigned)__popcll(K & 0xFULL);        if (r >= c) { r -= c; p2 += 4;  K >>= 4; }
            c = (unsigned)__popcll(K & 0x3ULL);        if (r >= c) { r -= c; p2 += 2;  K >>= 2; }
            c = (unsigned)__popcll(K & 0x1ULL);        if (r >= c) { r -= c; p2 += 1; }
            unsigned p = (w << 6) | p2;
            oi = cidx[base + p];
            x1 = wx1[base + p]; y1 = wy1[base + p];
            x2 = wx2[base + p]; y2 = wy2[base + p];
        }
        float sc = Cb[2 * oi + 1];
        float* ob = out + ((size_t)b * MAXP + t) * 4;
        ob[0] = x1; ob[1] = y1; ob[2] = x2; ob[3] = y2;
        out[(size_t)BB * MAXP * 4 + (size_t)b * MAXP + t] = sc;
    }
}

// ============ Guarded full fallback (round-2 monolithic, validated) ============
#define CH 64
#define TPC (CH / EPT)
__global__ __launch_bounds__(NT) void nms_fallback(const float* __restrict__ proposals,
                                                   const float* __restrict__ cls,
                                                   const unsigned* __restrict__ need1,
                                                   float* __restrict__ out) {
    __shared__ unsigned long long skeys[NN];
    __shared__ unsigned char ssup[NN];
    __shared__ float cbx1[2][CH], cby1[2][CH], cbx2[2][CH], cby2[2][CH], cbar[2][CH];
    __shared__ unsigned long long skept[2];
    __shared__ unsigned int ssel[MAXP];
    __shared__ unsigned int swsum[NT / 64];
    __shared__ unsigned int s_nvalid;
    __shared__ unsigned int s_nk;

    const int b = blockIdx.x;
    if (need1 && !need1[b]) return;
    const int tid = threadIdx.x;
    const float* Pb = proposals + (size_t)b * NN * 4;
    const float* Cb = cls + (size_t)b * NN * 2;

    if (tid == 0) s_nvalid = 0;
    __syncthreads();

    unsigned lv = 0;
    for (int i = tid; i < NN; i += NT) {
        float sc = Cb[i * 2 + 1];
        bool valid = sc > SCORE_THR;
        unsigned mb = valid ? (__float_as_uint(sc) | 0x80000000u) : 0u;
        skeys[i] = ((unsigned long long)mb << 32) | (unsigned)(~i);
        lv += valid ? 1u : 0u;
    }
    for (int off = 32; off > 0; off >>= 1) lv += __shfl_down(lv, off, 64);
    if ((tid & 63) == 0) atomicAdd(&s_nvalid, lv);

    for (unsigned k = 2; k <= NN; k <<= 1) {
        for (unsigned j = k >> 1; j > 0; j >>= 1) {
            __syncthreads();
            for (unsigned p = tid; p < NN / 2; p += NT) {
                unsigned low = p & (j - 1);
                unsigned i = ((p ^ low) << 1) | low;
                unsigned ixj = i | j;
                unsigned long long a = skeys[i], c = skeys[ixj];
                if ((a < c) == ((i & k) == 0)) { skeys[i] = c; skeys[ixj] = a; }
            }
        }
    }
    __syncthreads();

    const unsigned n_valid = s_nvalid;

    unsigned ordj[EPT];
    float bx1[EPT], by1[EPT], bx2[EPT], by2[EPT], bar[EPT];
    int rflag[EPT];
    for (int c2 = 0; c2 < EPT; ++c2) {
        int j = tid * EPT + c2;
        unsigned oi = ~(unsigned)skeys[j];
        ordj[c2] = oi;
        const float* P = Pb + (size_t)oi * 4;
        float x1 = P[0], y1 = P[1], x2 = P[2], y2 = P[3];
        bx1[c2] = x1; by1[c2] = y1; bx2[c2] = x2; by2[c2] = y2;
        bar[c2] = __fmul_rn(__fsub_rn(x2, x1), __fsub_rn(y2, y1));
        int sup = (j < (int)n_valid) ? 0 : 1;
        rflag[c2] = sup;
        ssup[j] = (unsigned char)sup;
    }

    const unsigned nch = (n_valid + CH - 1) / CH;
    for (unsigned c = 0; c < nch; ++c) {
        const int p = (int)(c & 1);
        if (tid >= (int)(TPC * c) && tid < (int)(TPC * (c + 1))) {
            int bse = (tid - TPC * c) * EPT;
            #pragma unroll
            for (int c2 = 0; c2 < EPT; ++c2) {
                int l = bse + c2;
                cbx1[p][l] = bx1[c2]; cby1[p][l] = by1[c2];
                cbx2[p][l] = bx2[c2]; cby2[p][l] = by2[c2];
                cbar[p][l] = bar[c2];
            }
        }
        __syncthreads();

        if (tid < CH) {
            const int l = tid;
            const int j = (int)(c * CH) + l;
            float x1 = cbx1[p][l], y1 = cby1[p][l], x2 = cbx2[p][l], y2 = cby2[p][l];
            float ar = cbar[p][l];
            int supl = ssup[j];
            unsigned long long row = 0ULL;
            for (int m = l + 1; m < CH; ++m) {
                bool s = iou_ge(x1, y1, x2, y2, ar,
                                cbx1[p][m], cby1[p][m], cbx2[p][m], cby2[p][m], cbar[p][m]);
                if (s) row |= (1ULL << m);
            }
            unsigned long long S = __ballot(supl != 0);
            for (int i = 0; i < CH; ++i) {
                unsigned long long ri = __shfl(row, i, 64);
                if (!((S >> i) & 1ULL)) S |= ri;
            }
            ssup[j] = (unsigned char)((S >> l) & 1ULL);
            if (l == 0) skept[p] = ~S;
        }
        __syncthreads();

        const int myFirst = tid * EPT;
        if (myFirst >= (int)(CH * (c + 1)) &&
            !(rflag[0] & rflag[1] & rflag[2] & rflag[3])) {
            unsigned long long K = skept[p];
            while (K) {
                int m = __builtin_ctzll(K);
                K &= K - 1;
                float mx1 = cbx1[p][m], my1 = cby1[p][m];
                float mx2 = cbx2[p][m], my2 = cby2[p][m];
                float ma = cbar[p][m];
                #pragma unroll
                for (int c2 = 0; c2 < EPT; ++c2) {
                    if (!rflag[c2]) {
                        bool s = iou_ge(mx1, my1, mx2, my2, ma,
                                        bx1[c2], by1[c2], bx2[c2], by2[c2], bar[c2]);
                        if (s) { rflag[c2] = 1; ssup[myFirst + c2] = 1; }
                    }
                }
            }
        }
    }
    __syncthreads();

    unsigned kflag[EPT];
    unsigned lc = 0;
    for (int c2 = 0; c2 < EPT; ++c2) {
        int j = tid * EPT + c2;
        kflag[c2] = ssup[j] ? 0u : 1u;
        lc += kflag[c2];
    }
    unsigned lane = tid & 63, wid = tid >> 6;
    unsigned inc = lc;
    for (int off = 1; off < 64; off <<= 1) {
        unsigned o = __shfl_up(inc, off, 64);
        if (lane >= (unsigned)off) inc += o;
    }
    if (lane == 63) swsum[wid] = inc;
    __syncthreads();
    if (tid == 0) {
        unsigned run = 0;
        for (int w = 0; w < NT / 64; ++w) { unsigned t = swsum[w]; swsum[w] = run; run += t; }
        s_nk = run;
    }
    __syncthreads();
    unsigned bse = swsum[wid] + (inc - lc);
    for (int c2 = 0; c2 < EPT; ++c2) {
        if (kflag[c2]) {
            if (bse < MAXP) ssel[bse] = ordj[c2];
            ++bse;
        }
    }
    const unsigned nk_pre = s_nk;
    __syncthreads();

    if (tid < MAXP) {
        if (nk_pre == 0) {
            ssel[tid] = ~(unsigned)skeys[NN - 1];
        } else if (tid >= nk_pre) {
            ssel[tid] = ssel[nk_pre - 1];
        }
    }
    __syncthreads();

    if (tid < MAXP) {
        unsigned si = ssel[tid];
        const float* P = Pb + (size_t)si * 4;
        float* ob = out + ((size_t)b * MAXP + tid) * 4;
        ob[0] = P[0]; ob[1] = P[1]; ob[2] = P[2]; ob[3] = P[3];
        out[(size_t)BB * MAXP * 4 + (size_t)b * MAXP + tid] = Cb[si * 2 + 1];
    }
}

extern "C" void kernel_launch(void* const* d_in, const int* in_sizes, int n_in,
                              void* d_out, int out_size, void* d_ws, size_t ws_size,
                              hipStream_t stream) {
    const float* proposals = (const float*)d_in[0];
    const float* cls = (const float*)d_in[1];
    float* out = (float*)d_out;

    const size_t S = (size_t)BB * RTOP;
    const size_t need_sz = S * RW * sizeof(ull)       // m8
                         + S * 5 * sizeof(float)      // SoA
                         + S * sizeof(unsigned)       // cidx
                         + 3 * BB * sizeof(unsigned) + 256;
    if (ws_size < need_sz) {
        nms_fallback<<<BB, NT, 0, stream>>>(proposals, cls, (const unsigned*)nullptr, out);
        return;
    }

    ull* m8 = (ull*)d_ws;                             // 512 KB
    float* wx1 = (float*)(m8 + S * RW);
    float* wy1 = wx1 + S;
    float* wx2 = wy1 + S;
    float* wy2 = wx2 + S;
    float* war = wy2 + S;
    unsigned* cidx = (unsigned*)(war + S);
    unsigned* wnv = cidx + S;
    unsigned* need0 = wnv + BB;
    unsigned* need1 = need0 + BB;

    filter_sort_kernel<<<BB, FNT, 0, stream>>>(proposals, cls, wx1, wy1, wx2, wy2, war,
                                               cidx, wnv, need0);
    mask512_kernel<<<dim3(MBPI, BB), 256, 0, stream>>>(wx1, wy1, wx2, wy2, war, wnv, m8);
    scan_out_kernel<<<BB, SNT3, 0, stream>>>(proposals, cls, wx1, wy1, wx2, wy2,
                                             cidx, wnv, need0, need1, m8, out);
    nms_fallback<<<BB, NT, 0, stream>>>(proposals, cls, need1, out);   // no-op unless flagged
}